// Round 8
// baseline (39.369 us; speedup 1.0000x reference)
//
#include <hip/hip_runtime.h>

#define BB 32
#define CC 3
#define HH 512
#define WW 512

typedef float f32x2 __attribute__((ext_vector_type(2)));
typedef float f32x4 __attribute__((ext_vector_type(4)));

// 16384 blocks x 256 threads x 2 px/thread (rows h0, h0+1; 256-px half-row).
// - XCD swizzle (R3/R4): XCD k = blockIdx.x % 8 owns 4 whole batch images.
// - Paired 8B corner loads (R5): 2 gathers per (row,channel) pair.
// - R8: LDS store-exchange. Loads untouched; results staged in 6KB LDS and
//   written as dense dwordx4 stores (1KB/wave-instr instead of 256B).
//   VMEM instructions per thread: 18 -> 13.5. Tests the VMEM-issue-bound
//   theory with the load path held byte-identical to R7.
__global__ __launch_bounds__(256) void warp_kernel(const float* __restrict__ img,
                                                   const float* __restrict__ Htf,
                                                   float* __restrict__ out) {
    const int HW = HH * WW;
    __shared__ __align__(16) float sm[6][256];   // [c*2+j][px-in-half-row]

    int lb  = (blockIdx.x & 7) * 2048 + (blockIdx.x >> 3);  // logical block, 0..16383
    int b   = lb >> 9;                                      // 512 blocks per batch
    int rem = lb & 511;                                     // 256 row-pairs x 2 halves
    int h0  = (rem >> 1) * 2;
    int pxbase = (rem & 1) * 256;
    int tid = threadIdx.x;
    int w   = pxbase + tid;

    // b uniform across block -> scalar loads
    const float* Hp = Htf + b * 9;
    float h00 = Hp[0], h01 = Hp[1], h02 = Hp[2];
    float h10 = Hp[3], h11 = Hp[4], h12 = Hp[5];
    float h20 = Hp[6], h21 = Hp[7], h22 = Hp[8];

    float gx = -1.0f + 2.0f * (float)w / (float)(WW - 1);

    float wts[2][4];
    int   offA[2], offB[2];
    bool  clipx[2], hi[2];

#pragma unroll
    for (int j = 0; j < 2; ++j) {
        int h = h0 + j;
        float gy = -1.0f + 2.0f * (float)h / (float)(HH - 1);

        float X = h00 * gx + h01 * gy + h02;
        float Y = h10 * gx + h11 * gy + h12;
        float T = h20 * gx + h21 * gy + h22;
        float rT = 1.0f / T;
        float x = X * rT;
        float y = Y * rT;

        float px = (x + 1.0f) * (WW * 0.5f);
        float py = (y + 1.0f) * (HH * 0.5f);

        float fxf = floorf(px), fyf = floorf(py);
        float x0 = fminf(fmaxf(fxf,        0.0f), (float)(WW - 1));
        float x1 = fminf(fmaxf(fxf + 1.0f, 0.0f), (float)(WW - 1));
        float y0 = fminf(fmaxf(fyf,        0.0f), (float)(HH - 1));
        float y1 = fminf(fmaxf(fyf + 1.0f, 0.0f), (float)(HH - 1));

        wts[j][0] = (x1 - px) * (y1 - py);   // wa
        wts[j][1] = (x1 - px) * (py - y0);   // wb
        wts[j][2] = (px - x0) * (y1 - py);   // wc
        wts[j][3] = (px - x0) * (y1 - py);   // placeholder, fixed below
        wts[j][3] = (px - x0) * (py - y0);   // wd

        int ix0 = (int)x0, ix1 = (int)x1, iy0 = (int)y0, iy1 = (int)y1;
        clipx[j] = (ix1 == ix0);
        hi[j]    = (ix0 == WW - 1);
        int ix0m = min(ix0, WW - 2);
        offA[j] = iy0 * WW + ix0m;
        offB[j] = iy1 * WW + ix0m;
    }

    const float* ib = img + (size_t)b * (CC * HW);

    // Issue all 12 gather loads before any arithmetic consumes them.
    f32x2 fa[2][CC], fb[2][CC];
#pragma unroll
    for (int c = 0; c < CC; ++c) {
        const float* p = ib + c * HW;
#pragma unroll
        for (int j = 0; j < 2; ++j) {
            __builtin_memcpy(&fa[j][c], p + offA[j], 8);
            __builtin_memcpy(&fb[j][c], p + offB[j], 8);
        }
    }

#pragma unroll
    for (int c = 0; c < CC; ++c) {
#pragma unroll
        for (int j = 0; j < 2; ++j) {
            float A  = hi[j]    ? fa[j][c].y : fa[j][c].x;
            float Cv = clipx[j] ? A          : fa[j][c].y;
            float Bv = hi[j]    ? fb[j][c].y : fb[j][c].x;
            float Dv = clipx[j] ? Bv         : fb[j][c].y;
            float v = wts[j][0] * A + wts[j][1] * Bv + wts[j][2] * Cv + wts[j][3] * Dv;
            sm[c * 2 + j][tid] = v;
        }
    }

    __syncthreads();

    // Dense store phase: 384 vec4s (6 segments x 64), 1.5 per thread.
    float* outb = out + (size_t)b * (CC * HW);
    const float* smf = &sm[0][0];
    {
        int v0 = tid;                 // vec4 id 0..255
        int s = v0 >> 6, q = v0 & 63;
        int c = s >> 1, j = s & 1;
        f32x4 t = *reinterpret_cast<const f32x4*>(smf + s * 256 + 4 * q);
        *reinterpret_cast<f32x4*>(outb + (size_t)c * HW + (h0 + j) * WW + pxbase + 4 * q) = t;
    }
    if (tid < 128) {
        int v1 = tid + 256;           // vec4 id 256..383
        int s = v1 >> 6, q = v1 & 63;
        int c = s >> 1, j = s & 1;
        f32x4 t = *reinterpret_cast<const f32x4*>(smf + s * 256 + 4 * q);
        *reinterpret_cast<f32x4*>(outb + (size_t)c * HW + (h0 + j) * WW + pxbase + 4 * q) = t;
    }
}

extern "C" void kernel_launch(void* const* d_in, const int* in_sizes, int n_in,
                              void* d_out, int out_size, void* d_ws, size_t ws_size,
                              hipStream_t stream) {
    const float* img = (const float*)d_in[0];
    const float* Htf = (const float*)d_in[1];
    float* out = (float*)d_out;

    int blocks = (BB * HH * WW) / (256 * 2);   // 16384
    warp_kernel<<<blocks, 256, 0, stream>>>(img, Htf, out);
}